// Round 1
// baseline (398.853 us; speedup 1.0000x reference)
//
#include <hip/hip_runtime.h>

#define N_NODES 50000
#define N_EDGES 800000
#define D 64

// ---------------------------------------------------------------------------
// Kernel A: lin = data @ W_lin^T + b_lin     [N,64] = [N,64]x[64,64]^T
// blockDim = (64,4): lane = output column, y = row-within-block.
// W is staged transposed in LDS so lane c reads Ws[k*64+c] (conflict-free).
// data[r*64+k] is wave-uniform (r,k uniform across the 64-lane wave) -> s_load.
// ---------------------------------------------------------------------------
__global__ void lin_kernel(const float* __restrict__ data,
                           const float* __restrict__ W,
                           const float* __restrict__ b,
                           float* __restrict__ lin) {
    __shared__ float Ws[D * D];
    __shared__ float bs[D];
    int tid = threadIdx.y * 64 + threadIdx.x;
    for (int i = tid; i < D * D; i += 256) {
        int c = i >> 6, k = i & 63;
        Ws[k * 64 + c] = W[i];          // store transposed
    }
    if (threadIdx.y == 0) bs[threadIdx.x] = b[threadIdx.x];
    __syncthreads();

    int c = threadIdx.x;
    for (int r = blockIdx.x * 4 + threadIdx.y; r < N_NODES; r += gridDim.x * 4) {
        const float* drow = data + (size_t)r * D;
        float acc = bs[c];
#pragma unroll
        for (int k = 0; k < D; k++) acc += drow[k] * Ws[k * 64 + c];
        lin[(size_t)r * D + c] = acc;
    }
}

// ---------------------------------------------------------------------------
// Kernel B: edge scatter. One 64-lane wave per edge; lane = column.
//   S[tgt] += lin[src]   (64 coalesced fp32 atomics per edge)
//   deg[tgt] += 1        (lane 0)
// src/tgt loads are wave-uniform.
// ---------------------------------------------------------------------------
__global__ void scatter_kernel(const int* __restrict__ src,
                               const int* __restrict__ tgt,
                               const float* __restrict__ lin,
                               float* __restrict__ S,
                               int* __restrict__ deg) {
    int gtid = blockIdx.x * blockDim.x + threadIdx.x;
    int e = gtid >> 6;                 // edge handled by this wave
    int lane = threadIdx.x & 63;
    if (e >= N_EDGES) return;
    int s = src[e];
    int t = tgt[e];
    if (lane == 0) atomicAdd(&deg[t], 1);
    float v = lin[(size_t)s * D + lane];
    atomicAdd(&S[(size_t)t * D + lane], v);
}

// ---------------------------------------------------------------------------
// Kernel C: out = relu( (deg>0 ? lin - S/deg : 0) + merge @ W_tr^T + b_tr )
// Same layout as kernel A, epilogue fused.
// ---------------------------------------------------------------------------
__global__ void out_kernel(const float* __restrict__ merge,
                           const float* __restrict__ W,
                           const float* __restrict__ b,
                           const float* __restrict__ lin,
                           const float* __restrict__ S,
                           const int* __restrict__ deg,
                           float* __restrict__ out) {
    __shared__ float Ws[D * D];
    __shared__ float bs[D];
    int tid = threadIdx.y * 64 + threadIdx.x;
    for (int i = tid; i < D * D; i += 256) {
        int c = i >> 6, k = i & 63;
        Ws[k * 64 + c] = W[i];
    }
    if (threadIdx.y == 0) bs[threadIdx.x] = b[threadIdx.x];
    __syncthreads();

    int c = threadIdx.x;
    for (int r = blockIdx.x * 4 + threadIdx.y; r < N_NODES; r += gridDim.x * 4) {
        const float* mrow = merge + (size_t)r * D;
        float acc = bs[c];
#pragma unroll
        for (int k = 0; k < D; k++) acc += mrow[k] * Ws[k * 64 + c];
        int dg = deg[r];
        float lap = 0.0f;
        if (dg > 0)
            lap = lin[(size_t)r * D + c] - S[(size_t)r * D + c] / (float)dg;
        float o = lap + acc;
        out[(size_t)r * D + c] = o > 0.0f ? o : 0.0f;
    }
}

extern "C" void kernel_launch(void* const* d_in, const int* in_sizes, int n_in,
                              void* d_out, int out_size, void* d_ws, size_t ws_size,
                              hipStream_t stream) {
    const float* data  = (const float*)d_in[0];
    const float* merge = (const float*)d_in[1];
    const int*   src   = (const int*)d_in[2];
    const int*   tgt   = (const int*)d_in[3];
    const float* W_lin = (const float*)d_in[4];
    const float* b_lin = (const float*)d_in[5];
    const float* W_tr  = (const float*)d_in[6];
    const float* b_tr  = (const float*)d_in[7];
    float* out = (float*)d_out;

    // Workspace layout: lin [N*D f32] | S [N*D f32] | deg [N i32]
    char* ws = (char*)d_ws;
    float* lin = (float*)ws;
    float* S   = (float*)(ws + (size_t)N_NODES * D * sizeof(float));
    int*   deg = (int*)  (ws + 2 * (size_t)N_NODES * D * sizeof(float));

    // Zero S + deg (contiguous region); lin is fully overwritten, no memset.
    hipMemsetAsync(S, 0, (size_t)N_NODES * D * sizeof(float) + N_NODES * sizeof(int),
                   stream);

    lin_kernel<<<1024, dim3(64, 4), 0, stream>>>(data, W_lin, b_lin, lin);

    int scatter_blocks = (N_EDGES * 64 + 255) / 256;   // 1 wave per edge
    scatter_kernel<<<scatter_blocks, 256, 0, stream>>>(src, tgt, lin, S, deg);

    out_kernel<<<1024, dim3(64, 4), 0, stream>>>(merge, W_tr, b_tr, lin, S, deg, out);
}

// Round 2
// 313.780 us; speedup vs baseline: 1.2711x; 1.2711x over previous
//
#include <hip/hip_runtime.h>
#include <hip/hip_fp16.h>

#define N_NODES 50000
#define N_EDGES 800000
#define D 64

// ---------------------------------------------------------------------------
// Kernel A: lin = data @ W_lin^T + b_lin  (fp32), plus fp16 copy for scatter.
// blockDim = (64,4): lane = output column, y = row slot.
// Row staged in-register: one coalesced load, then __shfl broadcast per k
// (uniform k -> v_readlane + sgpr-operand FMA; no LDS, no barrier).
// ---------------------------------------------------------------------------
__global__ void lin_kernel(const float* __restrict__ data,
                           const float* __restrict__ W,
                           const float* __restrict__ b,
                           float* __restrict__ lin,
                           __half* __restrict__ lin16) {
    __shared__ float Ws[D * D];
    __shared__ float bs[D];
    int tid = threadIdx.y * 64 + threadIdx.x;
    for (int i = tid; i < D * D; i += 256) {
        int c = i >> 6, k = i & 63;
        Ws[k * 64 + c] = W[i];          // store transposed: Ws[k*64+c] = W[c][k]
    }
    if (threadIdx.y == 0) bs[threadIdx.x] = b[threadIdx.x];
    __syncthreads();

    int lane = threadIdx.x;
    for (int r = blockIdx.x * 4 + threadIdx.y; r < N_NODES; r += gridDim.x * 4) {
        float rv = data[(size_t)r * D + lane];   // coalesced: lane = k
        float acc = bs[lane];
#pragma unroll
        for (int k = 0; k < D; k++)
            acc += __shfl(rv, k) * Ws[k * 64 + lane];
        lin[(size_t)r * D + lane] = acc;
        lin16[(size_t)r * D + lane] = __float2half(acc);
    }
}

// ---------------------------------------------------------------------------
// Kernel B: edge scatter with packed-fp16 atomics.
// One 64-lane wave handles TWO edges: lanes 0-31 -> edge 2w, lanes 32-63 ->
// edge 2w+1. Each lane moves one __half2 (2 columns): gather lin16[src],
// global_atomic_pk_add_f16 into S16[tgt]. deg bumped by one lane per edge.
// 800K edges -> 400K waves, 25.6M atomic dwords (vs 51.2M fp32).
// ---------------------------------------------------------------------------
__global__ __launch_bounds__(256) void scatter_kernel(
        const int* __restrict__ src,
        const int* __restrict__ tgt,
        const __half2* __restrict__ lin16,
        __half2* __restrict__ S,
        int* __restrict__ deg) {
    int wid  = (blockIdx.x * 256 + threadIdx.x) >> 6;   // wave id = pair id
    int lane = threadIdx.x & 63;
    int e = wid * 2 + (lane >> 5);                      // edge for this half-wave
    int c = lane & 31;                                  // half2 column index
    int s = src[e];
    int t = tgt[e];
    if (c == 0) atomicAdd(&deg[t], 1);
    __half2 v = lin16[(size_t)s * 32 + c];
    unsafeAtomicAdd(&S[(size_t)t * 32 + c], v);
}

// ---------------------------------------------------------------------------
// Kernel C: out = relu( (deg>0 ? lin - S/deg : 0) + merge @ W_tr^T + b_tr )
// ---------------------------------------------------------------------------
__global__ void out_kernel(const float* __restrict__ merge,
                           const float* __restrict__ W,
                           const float* __restrict__ b,
                           const float* __restrict__ lin,
                           const __half* __restrict__ S16,
                           const int* __restrict__ deg,
                           float* __restrict__ out) {
    __shared__ float Ws[D * D];
    __shared__ float bs[D];
    int tid = threadIdx.y * 64 + threadIdx.x;
    for (int i = tid; i < D * D; i += 256) {
        int c = i >> 6, k = i & 63;
        Ws[k * 64 + c] = W[i];
    }
    if (threadIdx.y == 0) bs[threadIdx.x] = b[threadIdx.x];
    __syncthreads();

    int lane = threadIdx.x;
    for (int r = blockIdx.x * 4 + threadIdx.y; r < N_NODES; r += gridDim.x * 4) {
        float rv = merge[(size_t)r * D + lane];
        float acc = bs[lane];
#pragma unroll
        for (int k = 0; k < D; k++)
            acc += __shfl(rv, k) * Ws[k * 64 + lane];
        int dg = deg[r];
        float lap = 0.0f;
        if (dg > 0) {
            float sv = __half2float(S16[(size_t)r * D + lane]);
            lap = lin[(size_t)r * D + lane] - sv / (float)dg;
        }
        float o = lap + acc;
        out[(size_t)r * D + lane] = o > 0.0f ? o : 0.0f;
    }
}

extern "C" void kernel_launch(void* const* d_in, const int* in_sizes, int n_in,
                              void* d_out, int out_size, void* d_ws, size_t ws_size,
                              hipStream_t stream) {
    const float* data  = (const float*)d_in[0];
    const float* merge = (const float*)d_in[1];
    const int*   src   = (const int*)d_in[2];
    const int*   tgt   = (const int*)d_in[3];
    const float* W_lin = (const float*)d_in[4];
    const float* b_lin = (const float*)d_in[5];
    const float* W_tr  = (const float*)d_in[6];
    const float* b_tr  = (const float*)d_in[7];
    float* out = (float*)d_out;

    // Workspace: lin fp32 [N*D] | lin16 fp16 [N*D] | S16 fp16 [N*D] | deg i32 [N]
    char* ws = (char*)d_ws;
    float*  lin   = (float*)ws;
    __half* lin16 = (__half*)(ws + (size_t)N_NODES * D * 4);
    __half* S16   = (__half*)(ws + (size_t)N_NODES * D * 4 + (size_t)N_NODES * D * 2);
    int*    deg   = (int*)  (ws + (size_t)N_NODES * D * 4 + 2 * (size_t)N_NODES * D * 2);

    // Zero S16 + deg (contiguous).
    hipMemsetAsync(S16, 0, (size_t)N_NODES * D * 2 + N_NODES * sizeof(int), stream);

    lin_kernel<<<1024, dim3(64, 4), 0, stream>>>(data, W_lin, b_lin, lin, lin16);

    // 400K edge-pairs, 1 wave per pair, 4 waves per block -> 100K blocks.
    scatter_kernel<<<N_EDGES / 8, 256, 0, stream>>>(
        src, tgt, (const __half2*)lin16, (__half2*)S16, deg);

    out_kernel<<<1024, dim3(64, 4), 0, stream>>>(merge, W_tr, b_tr, lin, S16, deg, out);
}